// Round 9
// baseline (5113.815 us; speedup 1.0000x reference)
//
#include <hip/hip_runtime.h>

// VQ-VAE nearest centroid — bit-exact emulation of the reference fp32 pipeline.
//   S[i,k]  = single-accumulator ascending-d fp32 FMA chain (d = 0..255).
//   nx2/nc2 = plain sequential ascending sum r = fl(r + fl(v*v)) (mul+add, no FMA).
//   dist    = fl( fl(-2*S + nx2) + nc2 );  argmin strict-< (first min wins).
//
// Structure (R6, verified): 128x128 block tile, 16x16 threads, 8x8 accs/thread,
// 32-d chunks staged transposed in LDS ([quad][index], rows padded to 129),
// threads own stride-16 rows/cols. Argmin: per-thread ascending strict-< +
// lexico (dist,index) shuffle merge.
//
// R8: row-pad killed SQ_LDS_BANK_CONFLICT (1.17e8 -> 0) but dur ~unchanged:
// conflicts were off the critical path. R9 THEORY: VALUBusy 62% with
// Occupancy 21.5% = 2 waves/SIMD (__launch_bounds__(256,2) cap). Per-kc the
// staging (global latency ~600-900cy + 2 barrier drains) is serial with the
// 4096cy FMA block inside a wave; with only 1 partner wave/SIMD it can't be
// covered -> 4096/(4096+2400) ~ 63% busy, matching. Resources already fit
// 4 blocks/CU (LDS 38.4KB x4 = 153.6 <= 160KB; VGPR 108 <= 128-cap), so
// __launch_bounds__(256,4) doubles waves/SIMD -> TLP covers staging.

#define K_CENT 1024
#define DIM    256
#define BM     128           // rows per block
#define BN     128           // cols per tile iteration
#define NCT    (K_CENT/BN)   // 8 col tiles
#define NKC    (DIM/32)      // 8 k-chunks of 32 d's
#define LDP    (BM + 1)      // padded row stride (129) — bank-conflict fix

__device__ __forceinline__ float fmul(float a, float b) { return __fmul_rn(a, b); }
__device__ __forceinline__ float fadd(float a, float b) { return __fadd_rn(a, b); }

// ---- |c_k|^2: sequential ascending chain, one thread per centroid ----
__global__ __launch_bounds__(256)
void nc2_kernel(const float* __restrict__ c, float* __restrict__ nc2) {
    int k = blockIdx.x * blockDim.x + threadIdx.x;
    if (k >= K_CENT) return;
    const float* p = c + k * DIM;
    float r = 0.0f;
    #pragma unroll 1
    for (int d = 0; d < DIM; ++d) r = fadd(r, fmul(p[d], p[d]));
    nc2[k] = r;
}

__global__ __launch_bounds__(256, 4)
void vq_main(const float* __restrict__ x, const float* __restrict__ c,
             const float* __restrict__ nc2g, float* __restrict__ out) {
    const float4* __restrict__ x4 = (const float4*)x;
    const float4* __restrict__ c4 = (const float4*)c;
    float4* __restrict__ out4 = (float4*)out;

    __shared__ float4 xsT[8][LDP];    // [quad][row], padded
    __shared__ float4 csT[8][LDP];    // [quad][col], padded
    __shared__ float  cn2s[K_CENT];   // 4 KB
    __shared__ float  nxs[BM];
    __shared__ int    bidxs[BM];

    const int t  = threadIdx.x;
    const int tx = t & 15;            // owns cols {16i + tx}
    const int ty = t >> 4;            // owns rows {16j + ty}
    const int rowsBase = blockIdx.x * BM;

    #pragma unroll 1
    for (int i = t; i < K_CENT; i += 256) cn2s[i] = nc2g[i];

    float nxacc = 0.0f;               // row-t |x|^2 chain, built during ct==0

    float best[8]; int bi[8];
    #pragma unroll
    for (int j = 0; j < 8; ++j) { best[j] = 3.4e38f; bi[j] = 0; }

    #pragma unroll 1
    for (int ct = 0; ct < NCT; ++ct) {
        float acc[8][8];
        #pragma unroll
        for (int j = 0; j < 8; ++j)
            #pragma unroll
            for (int i = 0; i < 8; ++i) acc[j][i] = 0.0f;

        #pragma unroll 1
        for (int kc = 0; kc < NKC; ++kc) {
            __syncthreads();          // prev readers done before overwrite
            // stage 32-d chunk, transposed: linear l = p*256+t -> (row,quad)
            #pragma unroll
            for (int p = 0; p < 4; ++p) {
                int idx = (p << 8) + t;
                int r = idx >> 3, q = idx & 7;
                xsT[q][r] = x4[((rowsBase + r) << 6) + (kc << 3) + q];
                csT[q][r] = c4[(((ct << 7) + r) << 6) + (kc << 3) + q];
            }
            __syncthreads();

            // nx2: exact sequential chain, kc/q/comp ascending = d 0..255.
            if (ct == 0 && t < BM) {
                #pragma unroll
                for (int q = 0; q < 8; ++q) {
                    float4 v = xsT[q][t];
                    nxacc = fadd(nxacc, fmul(v.x, v.x));
                    nxacc = fadd(nxacc, fmul(v.y, v.y));
                    nxacc = fadd(nxacc, fmul(v.z, v.z));
                    nxacc = fadd(nxacc, fmul(v.w, v.w));
                }
                if (kc == NKC - 1) nxs[t] = nxacc;
            }

            #pragma unroll 2
            for (int dq = 0; dq < 8; ++dq) {
                float4 xv[8], cv[8];
                #pragma unroll
                for (int j = 0; j < 8; ++j) xv[j] = xsT[dq][(j << 4) + ty];
                #pragma unroll
                for (int i = 0; i < 8; ++i) cv[i] = csT[dq][(i << 4) + tx];
                #pragma unroll
                for (int j = 0; j < 8; ++j)
                    #pragma unroll
                    for (int i = 0; i < 8; ++i) {
                        float s = acc[j][i];          // ascending d: x,y,z,w
                        s = fmaf(xv[j].x, cv[i].x, s);
                        s = fmaf(xv[j].y, cv[i].y, s);
                        s = fmaf(xv[j].z, cv[i].z, s);
                        s = fmaf(xv[j].w, cv[i].w, s);
                        acc[j][i] = s;
                    }
            }
        }
        __syncthreads();              // publishes nxs (ct==0); tiles idle now

        // ---- dist + thread-local argmin (cols ascending -> first-min).
        #pragma unroll
        for (int j = 0; j < 8; ++j) {
            float nx2v = nxs[(j << 4) + ty];
            #pragma unroll
            for (int i = 0; i < 8; ++i) {
                int kg = (ct << 7) + (i << 4) + tx;
                float m = fadd(fadd(fmul(-2.0f, acc[j][i]), nx2v), cn2s[kg]);
                if (m < best[j]) { best[j] = m; bi[j] = kg; }
            }
        }
    }

    // ---- merge across the 16 tx lanes: lexicographic (dist, index) min
    // preserves the global first-min tie rule.
    #pragma unroll
    for (int j = 0; j < 8; ++j) {
        float b = best[j]; int ii = bi[j];
        #pragma unroll
        for (int m = 1; m <= 8; m <<= 1) {
            float ob = __shfl_xor(b, m, 64);
            int   oi = __shfl_xor(ii, m, 64);
            if (ob < b || (ob == b && oi < ii)) { b = ob; ii = oi; }
        }
        if (tx == 0) bidxs[(j << 4) + ty] = ii;
    }
    __syncthreads();

    // ---- coalesced gather: out[rows] = c[bidx[row]] (bit-copies).
    #pragma unroll
    for (int k = 0; k < 32; ++k) {
        int L = t + (k << 8);
        int r = L >> 6, v = L & 63;
        out4[((rowsBase + r) << 6) + v] = c4[(bidxs[r] << 6) + v];
    }
}

extern "C" void kernel_launch(void* const* d_in, const int* in_sizes, int n_in,
                              void* d_out, int out_size, void* d_ws, size_t ws_size,
                              hipStream_t stream) {
    const float* x = (const float*)d_in[0];
    const float* c = (const float*)d_in[1];
    float* out = (float*)d_out;
    float* nc2 = (float*)d_ws;           // 4 KiB scratch

    nc2_kernel<<<(K_CENT + 255) / 256, 256, 0, stream>>>(c, nc2);

    const int n_rows = in_sizes[0] / DIM;   // 131072
    vq_main<<<n_rows / BM, 256, 0, stream>>>(x, c, nc2, out);
}